// Round 13
// baseline (67.155 us; speedup 1.0000x reference)
//
#include <hip/hip_runtime.h>

#define NB 2
#define NN 1024
#define NK 64
#define NG 64
#define NF 128
#define NH 4
#define NO 128
#define PITCH 132   // ys pitch in k_projprep (bank-spread)

typedef unsigned short ushort_t;
typedef __attribute__((ext_vector_type(8))) short short8v;
typedef __attribute__((ext_vector_type(4))) float f32x4;

union FragU { uint4 u4; short8v s8; };

__device__ __forceinline__ float bf2f(ushort_t u) {
    union { unsigned int i; float f; } v; v.i = ((unsigned int)u) << 16; return v.f;
}
__device__ __forceinline__ ushort_t f2bf(float f) {
    unsigned int u = __float_as_uint(f);
    unsigned int r = 0x7fffu + ((u >> 16) & 1u);
    return (ushort_t)((u + r) >> 16);
}
// shifted softplus via hardware exp2/log2:
// ssp(x) = max(x,0) + ln2*log2(1 + 2^(-|x|*log2e)) - ln2; abs err ~1e-7.
__device__ __forceinline__ float sspf(float x) {
    const float u = __builtin_amdgcn_exp2f(-fabsf(x) * 1.44269504088896341f);
    return fmaxf(x, 0.f) + fmaf(0.69314718055994531f,
                                __builtin_amdgcn_logf(1.f + u),
                                -0.69314718055994531f);
}

// ---------------------------------------------------------------------------
// Kernel 1 (merged): blocks [0,256) = y-projection + attention dots;
// blocks [256,284) = weight prep (wf1/wf2 frag tables + w_out transpose).
// frag table layout: table[(fi*64+lane)*8+j], fi = ks*8+nf; element j maps to
// k = ks*32 + ((lane>>4)&3)*4 + (j&3) + 16*(j>>2), n = nf*16 + (lane&15).
// NOTE (round 13): because A- and B-fragments share the same per-lane layout,
// these tables serve equally as A-operands for the swapped (transposed) GEMMs.
// ---------------------------------------------------------------------------
__global__ __launch_bounds__(256) void k_projprep(
    const float* __restrict__ x,       // [B][N][F]
    const float* __restrict__ w_in2f,  // [H][F][F]
    const float* __restrict__ w_att,   // [H][2F]
    const float* __restrict__ wf1, const float* __restrict__ wf2,
    const float* __restrict__ w_out,
    ushort_t* __restrict__ y,          // [B][H][N][F] bf16
    float* __restrict__ a_c,           // [B][H][N]
    float* __restrict__ a_n,           // [B][H][N]
    ushort_t* __restrict__ wf1f, ushort_t* __restrict__ wf2f,
    float* __restrict__ w_outT)
{
    const int t = threadIdx.x;
    __shared__ float xs[8][NF];
    __shared__ float ys[32][PITCH];

    if (blockIdx.x >= 256) {
        // ---- prep path ----
        int s = (blockIdx.x - 256) * 256 + t;
        if (s >= 7168) return;
        if (s >= 3072) {
            const int s2 = s - 3072;           // [0,4096)
            const int o = s2 >> 5, fb = s2 & 31;
            #pragma unroll
            for (int j = 0; j < 4; ++j)
                w_outT[(size_t)o * NF + fb * 4 + j] = w_out[(size_t)(fb * 4 + j) * NO + o];
            return;
        }
        const float* W; ushort_t* out; int loOff;
        if (s < 1024) { W = wf1; out = wf1f; loOff = 8192; }
        else          { s -= 1024; W = wf2; out = wf2f; loOff = 16384; }
        const int fi = s >> 6, lane = s & 63;
        const int ks = fi >> 3, nf = fi & 7;
        const int n = nf * 16 + (lane & 15);
        const int kb = ks * 32 + ((lane >> 4) & 3) * 4;
        #pragma unroll
        for (int j = 0; j < 8; ++j) {
            const int k = kb + (j & 3) + ((j >> 2) << 4);
            const float v = W[(size_t)k * NF + n];
            const ushort_t hb = f2bf(v);
            out[(size_t)(fi * 64 + lane) * 8 + j] = hb;
            out[(size_t)loOff + (fi * 64 + lane) * 8 + j] = f2bf(v - bf2f(hb));
        }
        return;
    }

    // ---- projection path ----
    const int bn0 = blockIdx.x * 8;
    {
        const float4* src = (const float4*)(x + (size_t)bn0 * NF);
        float4* dst = (float4*)(&xs[0][0]);
        dst[t] = src[t];
    }
    __syncthreads();

    const int hp = t >> 7;
    const int f0 = t & 127;
    const int h0 = hp, h1 = hp + 2;
    const float* w0 = w_in2f + (size_t)h0 * NF * NF + f0;
    const float* w1 = w_in2f + (size_t)h1 * NF * NF + f0;
    float acc0[8], acc1[8];
    #pragma unroll
    for (int n = 0; n < 8; ++n) { acc0[n] = 0.f; acc1[n] = 0.f; }

    for (int i0 = 0; i0 < NF; i0 += 4) {
        float4 xv[8];
        #pragma unroll
        for (int n = 0; n < 8; ++n) xv[n] = *(const float4*)&xs[n][i0];
        #pragma unroll
        for (int ii = 0; ii < 4; ++ii) {
            const float wa = w0[(size_t)(i0 + ii) * NF];
            const float wb = w1[(size_t)(i0 + ii) * NF];
            #pragma unroll
            for (int n = 0; n < 8; ++n) {
                const float xi = (&xv[n].x)[ii];
                acc0[n] = fmaf(xi, wa, acc0[n]);
                acc1[n] = fmaf(xi, wb, acc1[n]);
            }
        }
    }
    #pragma unroll
    for (int n = 0; n < 8; ++n) {
        const int bn = bn0 + n;
        const int b = bn >> 10, nn = bn & (NN - 1);
        y[((size_t)(b * NH + h0) * NN + nn) * NF + f0] = f2bf(acc0[n]);
        y[((size_t)(b * NH + h1) * NN + nn) * NF + f0] = f2bf(acc1[n]);
        ys[n * 4 + h0][f0] = acc0[n];
        ys[n * 4 + h1][f0] = acc1[n];
    }
    __syncthreads();

    {
        const int hn = t >> 3, q = t & 7;
        const int h = hn & 3, n = hn >> 2;
        float pc = 0.f, pn = 0.f;
        #pragma unroll
        for (int j = 0; j < 16; ++j) {
            const int f = q + 8 * j;
            const float yv = ys[n * 4 + h][f];
            pc = fmaf(yv, w_att[h * 2 * NF + f], pc);
            pn = fmaf(yv, w_att[h * 2 * NF + NF + f], pn);
        }
        #pragma unroll
        for (int off = 1; off < 8; off <<= 1) {
            pc += __shfl_xor(pc, off, 8);
            pn += __shfl_xor(pn, off, 8);
        }
        if (q == 0) {
            const int bn = bn0 + n;
            const int b = bn >> 10, nn = bn & (NN - 1);
            a_c[(size_t)(b * NH + h) * NN + nn] = pc;
            a_n[(size_t)(b * NH + h) * NN + nn] = pn;
        }
    }
}

// ---------------------------------------------------------------------------
// Kernel 2 (round 13): all-register filter-net via operand-swapped MFMA.
//   W1^T = wf1^T @ fij^T   (A = wf1f table, B = fij from global, per-wave
//                           k-columns [16w,16w+16) -> waves read DISJOINT rows)
//   ssp + bias + repack    (pure register: C-frag of W1^T IS A2's B-frag)
//   W2^T = wf2^T @ W1^T    (A = wf2f table)
//   -> single LDS write of W2 (needed for cross-wave Phase C), 3 barriers.
// LDS map (22784 B):
//   [0     ..16896)  W2 [64][132] ushort
//   [16896 ..20992)  aggp [8][128] f32
//   [20992 ..21504)  aggc [128] f32
//   [21504 ..22528)  alpha [4][64] f32
//   [22528 ..22784)  nbs [64] int
// ---------------------------------------------------------------------------
__global__ __launch_bounds__(256, 5) void k_main(
    const int*      __restrict__ neighbors, // [B][N][K]
    const float*    __restrict__ pmask,     // [B][N][K]
    const float*    __restrict__ f_ij,      // [B][N][K][G]
    const float*    __restrict__ bf1,       // [F]
    const float*    __restrict__ bf2v,      // [F]
    const float*    __restrict__ w_outT,    // [O][F] transposed
    const float*    __restrict__ b_out,     // [O]
    const ushort_t* __restrict__ y,         // [B][H][N][F] bf16
    const float*    __restrict__ a_c,       // [B][H][N]
    const float*    __restrict__ a_n,       // [B][H][N]
    const ushort_t* __restrict__ wf1f,      // frag table hi/lo
    const ushort_t* __restrict__ wf2f,      // frag table hi
    float*          __restrict__ outp)      // [B][N][O]
{
    const int bn = blockIdx.x;
    const int b = bn >> 10, n_ = bn & (NN - 1);
    const int t = threadIdx.x;

    __shared__ __align__(16) char smem[22784];
    ushort_t* W2   = (ushort_t*)(smem);           // [64][132]
    float*    aggp = (float*)(smem + 16896);      // [8][128]
    float*    aggc = (float*)(smem + 20992);      // [128]
    float*    alpha = (float*)(smem + 21504);     // [4][64]
    int*      nbs   = (int*)(smem + 22528);       // [64]

    const int wave = t >> 6, lane = t & 63;
    const int lrow = lane & 15;
    const int lq   = (lane >> 4) & 3;
    const int myk  = wave * 16 + lrow;   // this lane's k (W2 row)

    if (t < NK) nbs[t] = neighbors[(size_t)bn * NK + t];

    // Hoisted Phase-B gather loads (latency hides under the GEMM chain).
    const int   mynb = neighbors[(size_t)bn * NK + lane];
    const float avc  = a_c[(size_t)(b * NH + wave) * NN + n_];
    const float avn  = a_n[(size_t)(b * NH + wave) * NN + mynb];
    const float pmk  = pmask[(size_t)bn * NK + lane];

    // ---- fij^T B-fragments: lane reads ITS k-row (disjoint across waves) ----
    FragU fB[2];
    {
        const float* frow = f_ij + (size_t)bn * NK * NG + (size_t)myk * NG;
        #pragma unroll
        for (int ks = 0; ks < 2; ++ks) {
            const float4 p0 = *(const float4*)(frow + ks * 32 + lq * 4);
            const float4 p1 = *(const float4*)(frow + ks * 32 + lq * 4 + 16);
            uint4 q;
            q.x = (unsigned)f2bf(p0.x) | ((unsigned)f2bf(p0.y) << 16);
            q.y = (unsigned)f2bf(p0.z) | ((unsigned)f2bf(p0.w) << 16);
            q.z = (unsigned)f2bf(p1.x) | ((unsigned)f2bf(p1.y) << 16);
            q.w = (unsigned)f2bf(p1.z) | ((unsigned)f2bf(p1.w) << 16);
            fB[ks].u4 = q;
        }
    }

    // ---- A1': cW1[it] = (wf1^T tile it) x fij^T, 2-term (wf1 hi+lo) ----
    f32x4 cW1[8];
    #pragma unroll
    for (int it = 0; it < 8; ++it) cW1[it] = (f32x4)0.f;
    #pragma unroll
    for (int ks = 0; ks < 2; ++ks) {
        #pragma unroll
        for (int it = 0; it < 8; ++it) {
            FragU ah, al;
            ah.u4 = *((const uint4*)wf1f + (ks * 8 + it) * 64 + lane);
            al.u4 = *((const uint4*)(wf1f + 8192) + (ks * 8 + it) * 64 + lane);
            cW1[it] = __builtin_amdgcn_mfma_f32_16x16x32_bf16(ah.s8, fB[ks].s8, cW1[it], 0, 0, 0);
            cW1[it] = __builtin_amdgcn_mfma_f32_16x16x32_bf16(al.s8, fB[ks].s8, cW1[it], 0, 0, 0);
        }
    }

    // ---- ssp + bias; repack C-frags (i in-register) into A2' B-frags ----
    // B-frag elem j <-> i = ks*32 + lq*4 + (j&3) + 16*(j>>2)
    //                    = rows of cW1[2ks] (j<4) and cW1[2ks+1] (j>=4).
    FragU w1B[4];
    #pragma unroll
    for (int ks = 0; ks < 4; ++ks) {
        unsigned e0[4], e1[4];
        #pragma unroll
        for (int j = 0; j < 4; ++j) {
            e0[j] = (unsigned)f2bf(sspf(cW1[2 * ks][j]     + bf1[(2 * ks) * 16     + lq * 4 + j]));
            e1[j] = (unsigned)f2bf(sspf(cW1[2 * ks + 1][j] + bf1[(2 * ks + 1) * 16 + lq * 4 + j]));
        }
        uint4 q;
        q.x = e0[0] | (e0[1] << 16);
        q.y = e0[2] | (e0[3] << 16);
        q.z = e1[0] | (e1[1] << 16);
        q.w = e1[2] | (e1[3] << 16);
        w1B[ks].u4 = q;
    }

    // ---- A2': cW2[ft] = (wf2^T tile ft) x W1^T, 1-term (wf2 hi) ----
    f32x4 cW2[8];
    #pragma unroll
    for (int ft = 0; ft < 8; ++ft) cW2[ft] = (f32x4)0.f;
    #pragma unroll
    for (int ks = 0; ks < 4; ++ks) {
        #pragma unroll
        for (int ft = 0; ft < 8; ++ft) {
            FragU a2;
            a2.u4 = *((const uint4*)wf2f + (ks * 8 + ft) * 64 + lane);
            cW2[ft] = __builtin_amdgcn_mfma_f32_16x16x32_bf16(a2.s8, w1B[ks].s8, cW2[ft], 0, 0, 0);
        }
    }

    // ---- write W2 rows to LDS (k = myk; 4 consecutive f per reg group) ----
    #pragma unroll
    for (int ft = 0; ft < 8; ++ft) {
        const int f0 = ft * 16 + lq * 4;
        uint2 pk;
        pk.x = (unsigned)f2bf(cW2[ft][0] + bf2v[f0])     | ((unsigned)f2bf(cW2[ft][1] + bf2v[f0 + 1]) << 16);
        pk.y = (unsigned)f2bf(cW2[ft][2] + bf2v[f0 + 2]) | ((unsigned)f2bf(cW2[ft][3] + bf2v[f0 + 3]) << 16);
        *(uint2*)&W2[myk * 132 + f0] = pk;
    }

    // ---- Phase B: attention softmax (wave == head), mask folded in ----
    {
        const float att = sspf(avc + avn);
        float m = att;
        #pragma unroll
        for (int off = 32; off > 0; off >>= 1) m = fmaxf(m, __shfl_xor(m, off, 64));
        const float e = __builtin_amdgcn_exp2f((att - m) * 1.44269504088896341f);
        float s = e;
        #pragma unroll
        for (int off = 32; off > 0; off >>= 1) s += __shfl_xor(s, off, 64);
        alpha[wave * 64 + lane] = (e / s) * pmk;
    }
    __syncthreads();                            // bar_a: W2 + alpha + nbs ready

    // ---- Phase C: agg[f] = (1/H) sum_k W2[k][f] * sum_h alpha[h][k]*y[b,h,nb,f] ----
    {
        const int fq = (t & 31) * 4;
        const int kg = t >> 5;          // 0..7
        float4 accv; accv.x = accv.y = accv.z = accv.w = 0.f;
        const ushort_t* yb = y + (size_t)b * NH * NN * NF;
        #pragma unroll 2
        for (int kk = 0; kk < 8; ++kk) {
            const int k = kg * 8 + kk;
            const int nb = nbs[k];
            const ushort_t* yp = yb + (size_t)nb * NF + fq;
            const uint2 u0 = *(const uint2*)(yp);
            const uint2 u1 = *(const uint2*)(yp + (size_t)NN * NF);
            const uint2 u2 = *(const uint2*)(yp + 2 * (size_t)NN * NF);
            const uint2 u3 = *(const uint2*)(yp + 3 * (size_t)NN * NF);
            const float a0 = alpha[0 * 64 + k], a1 = alpha[1 * 64 + k];
            const float a2 = alpha[2 * 64 + k], a3 = alpha[3 * 64 + k];
            float4 s;
            s.x = fmaf(a3, bf2f((ushort_t)(u3.x & 0xffffu)),
                  fmaf(a2, bf2f((ushort_t)(u2.x & 0xffffu)),
                  fmaf(a1, bf2f((ushort_t)(u1.x & 0xffffu)),
                       a0 * bf2f((ushort_t)(u0.x & 0xffffu)))));
            s.y = fmaf(a3, bf2f((ushort_t)(u3.x >> 16)),
                  fmaf(a2, bf2f((ushort_t)(u2.x >> 16)),
                  fmaf(a1, bf2f((ushort_t)(u1.x >> 16)),
                       a0 * bf2f((ushort_t)(u0.x >> 16)))));
            s.z = fmaf(a3, bf2f((ushort_t)(u3.y & 0xffffu)),
                  fmaf(a2, bf2f((ushort_t)(u2.y & 0xffffu)),
                  fmaf(a1, bf2f((ushort_t)(u1.y & 0xffffu)),
                       a0 * bf2f((ushort_t)(u0.y & 0xffffu)))));
            s.w = fmaf(a3, bf2f((ushort_t)(u3.y >> 16)),
                  fmaf(a2, bf2f((ushort_t)(u2.y >> 16)),
                  fmaf(a1, bf2f((ushort_t)(u1.y >> 16)),
                       a0 * bf2f((ushort_t)(u0.y >> 16)))));
            const uint2 wv = *(const uint2*)&W2[k * 132 + fq];
            accv.x = fmaf(bf2f((ushort_t)(wv.x & 0xffffu)), s.x, accv.x);
            accv.y = fmaf(bf2f((ushort_t)(wv.x >> 16)),     s.y, accv.y);
            accv.z = fmaf(bf2f((ushort_t)(wv.y & 0xffffu)), s.z, accv.z);
            accv.w = fmaf(bf2f((ushort_t)(wv.y >> 16)),     s.w, accv.w);
        }
        *(float4*)&aggp[kg * 128 + fq] = accv;  // own region, no overlay hazard
    }
    __syncthreads();                            // bar_b: aggp written
    if (t < NF) {
        float s = 0.f;
        #pragma unroll
        for (int q = 0; q < 8; ++q) s += aggp[q * 128 + t];
        aggc[t] = s * 0.25f;   // / H
    }
    __syncthreads();                            // bar_c

    // ---- Phase D: out = ssp(agg @ w_outT + b_out), vectorized loads ----
    if (t < NO) {
        float z = b_out[t];
        const float4* wr = (const float4*)(w_outT + (size_t)t * NF);
        #pragma unroll 8
        for (int q = 0; q < NF / 4; ++q) {
            const float4 w = wr[q];
            const float4 a = *(const float4*)&aggc[q * 4];
            z = fmaf(a.x, w.x, fmaf(a.y, w.y, fmaf(a.z, w.z, fmaf(a.w, w.w, z))));
        }
        outp[(size_t)bn * NO + t] = sspf(z);
    }
}

extern "C" void kernel_launch(void* const* d_in, const int* in_sizes, int n_in,
                              void* d_out, int out_size, void* d_ws, size_t ws_size,
                              hipStream_t stream) {
    const float* x      = (const float*)d_in[0];
    // d_in[1] = r_ij (unused by reference)
    const int*   nbr    = (const int*)d_in[2];
    const float* pmask  = (const float*)d_in[3];
    const float* f_ij   = (const float*)d_in[4];
    const float* w_in2f = (const float*)d_in[5];
    const float* w_att  = (const float*)d_in[6];
    const float* wf1    = (const float*)d_in[7];
    const float* bf1    = (const float*)d_in[8];
    const float* wf2    = (const float*)d_in[9];
    const float* bf2v   = (const float*)d_in[10];
    const float* w_out  = (const float*)d_in[11];
    const float* b_out  = (const float*)d_in[12];

    // ws layout (total ~2.22 MB):
    //   yb16  [B][H][N][F] bf16 : 2 MB
    //   a_c   [B][H][N] f32     : 32 KB
    //   a_n   [B][H][N] f32     : 32 KB
    //   wf1f  hi+lo bf16 tables : 32 KB
    //   wf2f  hi+lo bf16 tables : 64 KB
    //   w_outT [O][F] f32       : 64 KB
    ushort_t* yb16  = (ushort_t*)d_ws;
    float*    a_c   = (float*)(yb16 + (size_t)NB * NH * NN * NF);
    float*    a_n   = a_c + (size_t)NB * NH * NN;
    ushort_t* wf1f  = (ushort_t*)(a_n + (size_t)NB * NH * NN);
    ushort_t* wf2f  = wf1f + 16384;
    float*    w_outT = (float*)(wf2f + 32768);

    float* outp = (float*)d_out;

    k_projprep<<<NB * NN / 8 + 28, 256, 0, stream>>>(
        x, w_in2f, w_att, wf1, wf2, w_out, yb16, a_c, a_n, wf1f, wf2f, w_outT);
    k_main<<<NB * NN, 256, 0, stream>>>(nbr, pmask, f_ij, bf1, bf2v,
                                        w_outT, b_out, yb16, a_c, a_n, wf1f, wf2f, outp);
}